// Round 11
// baseline (420.573 us; speedup 1.0000x reference)
//
#include <hip/hip_runtime.h>
#include <hip/hip_bf16.h>
#include <math.h>

typedef __attribute__((ext_vector_type(8))) short bf16x8;
typedef __attribute__((ext_vector_type(4))) float f32x4;

#define NBATCH   2048
#define MTILES   64          // 32 batches (352 rows) each; 64*352 = 22528 exact
#define NTILES   24          // 128 cols each (4 pairs of 2x16)
#define NBLOCKS  (MTILES*NTILES)
#define EPI_STRIDE 5808      // floats per epilogue region (176*33)
#define STG2B    46464       // byte offset of stg2 area (2 regions * 896 floats)
#define ABYTES   22528       // 352 rows x 32 k bf16
#define BUFSZ    30720       // ABYTES + 8192 B of B
#define LDS_TOTAL (2*BUFSZ)  // 61440: double-buffered; 2 blocks/CU. epilogue aliases.

// A pre-packed bf16, MFMA-fragment-linear:
// [mtile 64][kstep 32][granule mf 0..21][lane 64][8]
__device__ unsigned short g_A[(size_t)MTILES*32*22*64*8];
// B packed bf16 fragment-linear: [g 192][kk 32][lane 64][8]
// g 0..31 = kW1, 32..63 = lW1, 64..127 = dW1a, 128..191 = dW1b
__device__ unsigned short g_wsB2[(size_t)192*32*64*8];
// kinetic/local partials, slot-major: [0..15] kinetic; 16 + j*11 + t local (j<16)
__device__ float g_partKL[(size_t)192*NBATCH];
// interaction partials: [j2 64][batch 2048][56] (full-line coalesced writes)
__device__ float g_partI[(size_t)64*NBATCH*56];

static constexpr int II_[55] = {
    0,0,0,0,0,0,0,0,0,0, 1,1,1,1,1,1,1,1,1, 2,2,2,2,2,2,2,2,
    3,3,3,3,3,3,3, 4,4,4,4,4,4, 5,5,5,5,5, 6,6,6,6, 7,7,7, 8,8, 9};
static constexpr int JJ_[55] = {
    1,2,3,4,5,6,7,8,9,10, 2,3,4,5,6,7,8,9,10, 3,4,5,6,7,8,9,10,
    4,5,6,7,8,9,10, 5,6,7,8,9,10, 6,7,8,9,10, 7,8,9,10, 8,9,10, 9,10, 10};

__device__ __forceinline__ unsigned short f32_to_bf16u(float f) {
    unsigned u = __float_as_uint(f);
    u += 0x7fffu + ((u >> 16) & 1u);
    return (unsigned short)(u >> 16);
}

// 96 pairs: pairIdx = n*4 + wnp. <16 kinetic, <32 local, else interaction.
__device__ __forceinline__ int gmap(int pairIdx, int nf) {
    if (pairIdx < 16) return 2*pairIdx + nf;
    if (pairIdx < 32) return 32 + 2*(pairIdx-16) + nf;
    const int j2 = pairIdx - 32;
    return (nf ? 128 : 64) + j2;
}

__global__ void pack_A(const float* __restrict__ h) {
    const int t = blockIdx.x*256 + threadIdx.x;
    const int row = t >> 7, k8 = t & 127;
    const float* src = h + (size_t)row*1024 + k8*8;
    f32x4 a = *(const f32x4*)src;
    f32x4 b = *(const f32x4*)(src + 4);
    bf16x8 v;
    v[0]=(short)f32_to_bf16u(a[0]); v[1]=(short)f32_to_bf16u(a[1]);
    v[2]=(short)f32_to_bf16u(a[2]); v[3]=(short)f32_to_bf16u(a[3]);
    v[4]=(short)f32_to_bf16u(b[0]); v[5]=(short)f32_to_bf16u(b[1]);
    v[6]=(short)f32_to_bf16u(b[2]); v[7]=(short)f32_to_bf16u(b[3]);
    const int mtile = row / 352;
    const int rr = row - mtile*352;
    const int mf = rr >> 4, lo = rr & 15;
    const int kstep = k8 >> 2, h4 = k8 & 3;
    const size_t di = ((((size_t)mtile*32 + kstep)*22 + mf)*64 + (h4*16 + lo))*8;
    *(bf16x8*)(g_A + di) = v;
}

__global__ void pack_weights(const float* __restrict__ kW1,
                             const float* __restrict__ lW1,
                             const float* __restrict__ dW1) {
    const int t = blockIdx.x * 256 + threadIdx.x;
    const int lane = t & 63;
    const int kk   = (t >> 6) & 31;
    const int g    = t >> 11;
    const int col  = g * 16 + (lane & 15);
    const int k0   = kk * 32 + (lane >> 4) * 8;
    const float* src; int ncol, c;
    if (col < 512)       { src = kW1;                        ncol = 512;  c = col; }
    else if (col < 1024) { src = lW1;                        ncol = 512;  c = col - 512; }
    else if (col < 2048) { src = dW1;                        ncol = 1024; c = col - 1024; }
    else                 { src = dW1 + (size_t)1024 * 1024;  ncol = 1024; c = col - 2048; }
    bf16x8 v;
    #pragma unroll
    for (int j = 0; j < 8; ++j)
        v[j] = (short)f32_to_bf16u(src[(size_t)(k0 + j) * ncol + c]);
    *(bf16x8*)(g_wsB2 + (size_t)t * 8) = v;
}

// init one granule slot: src ptr at step 0, per-step stride, LDS dst offset
#define INITG(gi, sp, st, dd) do { \
    if ((gi) < 22) { \
        sp = (const char*)g_A + (((size_t)m*32*22 + (gi))*64 + ln)*16; \
        st = 22*64*16; \
        dd = (gi)*1024; \
    } else { \
        const int jg = (gi) - 22; \
        const int G = gmap(n*4 + (jg >> 1), jg & 1); \
        sp = (const char*)g_wsB2 + (((size_t)G*32)*64 + ln)*16; \
        st = 64*16; \
        dd = ABYTES + jg*1024; \
    } \
} while(0)

#define GLL(sp, doff, bufbase) \
    __builtin_amdgcn_global_load_lds( \
        (const __attribute__((address_space(1))) unsigned int*)(sp), \
        (__attribute__((address_space(3))) unsigned int*)(smem + (bufbase) + (doff)), 16, 0, 0)

#define STAGE2(bufbase) do { \
    GLL(s0, d0, bufbase); s0 += st0; \
    GLL(s1, d1, bufbase); s1 += st1; \
    GLL(s2, d2, bufbase); s2 += st2; \
    GLL(s3, d3, bufbase); s3 += st3; \
} while(0)

#define MFMA_PHASE(bufbase) do { \
    const char* Ab = smem + (bufbase) + (wm*11)*1024 + ln*16; \
    const char* Bb = smem + (bufbase) + ABYTES + (wnp*2)*1024 + ln*16; \
    bf16x8 b0 = *(const bf16x8*)(Bb); \
    bf16x8 b1 = *(const bf16x8*)(Bb + 1024); \
    __builtin_amdgcn_s_setprio(1); \
    _Pragma("unroll") \
    for (int mf = 0; mf < 11; ++mf) { \
        bf16x8 af = *(const bf16x8*)(Ab + mf*1024); \
        accA[mf] = __builtin_amdgcn_mfma_f32_16x16x32_bf16(af, b0, accA[mf], 0,0,0); \
        accB[mf] = __builtin_amdgcn_mfma_f32_16x16x32_bf16(af, b1, accB[mf], 0,0,0); \
    } \
    __builtin_amdgcn_s_setprio(0); \
} while(0)

#define EPILOGUE() do { \
  float* stg = (float*)smem + (wnp >> 1) * EPI_STRIDE; \
  if (pairIdx < 32) { \
    const bool kin = pairIdx < 16; \
    const float* b1a = kin ? kb1 : lb1; \
    const float* w2a = kin ? kW2 : lW2; \
    const int c0 = (kin ? pairIdx : (pairIdx - 16)) * 32; \
    const float b1v0 = b1a[c0 + lo16],      w2v0 = w2a[c0 + lo16]; \
    const float b1v1 = b1a[c0 + 16 + lo16], w2v1 = w2a[c0 + 16 + lo16]; \
    _Pragma("unroll") \
    for (int mf = 0; mf < 11; ++mf) { \
      _Pragma("unroll") \
      for (int e = 0; e < 4; ++e) { \
        const int r = mf*16 + 4*hi4 + e; \
        stg[r*33 + lo16]      = fmaxf(accA[mf][e] + b1v0, 0.f) * w2v0; \
        stg[r*33 + 16 + lo16] = fmaxf(accB[mf][e] + b1v1, 0.f) * w2v1; \
      } } \
    asm volatile("s_waitcnt lgkmcnt(0)" ::: "memory"); \
    float rs0 = 0.f, rs1 = 0.f, rs2 = 0.f; \
    _Pragma("unroll") \
    for (int c = 0; c < 32; ++c) { \
      rs0 += stg[ln*33 + c]; \
      rs1 += stg[(ln + 64)*33 + c]; \
      if (ln < 48) rs2 += stg[(ln + 128)*33 + c]; \
    } \
    if (kin) { \
      asm volatile("s_waitcnt lgkmcnt(0)" ::: "memory"); \
      stg[ln] = rs0; stg[ln + 64] = rs1; \
      if (ln < 48) stg[ln + 128] = rs2; \
      asm volatile("s_waitcnt lgkmcnt(0)" ::: "memory"); \
      if (ln < 16) { \
        float s = 0.f; \
        _Pragma("unroll") \
        for (int t = 0; t < 11; ++t) s += stg[ln*11 + t]; \
        g_partKL[(size_t)pairIdx*NBATCH + bg0 + ln] = s; \
      } \
    } else { \
      const int base = 16 + (pairIdx - 16)*11; \
      { const int r = ln;       const int bb = (r*373)>>12; const int t = r - bb*11; \
        g_partKL[(size_t)(base + t)*NBATCH + bg0 + bb] = rs0; } \
      { const int r = ln + 64;  const int bb = (r*373)>>12; const int t = r - bb*11; \
        g_partKL[(size_t)(base + t)*NBATCH + bg0 + bb] = rs1; } \
      if (ln < 48) { \
        const int r = ln + 128; const int bb = (r*373)>>12; const int t = r - bb*11; \
        g_partKL[(size_t)(base + t)*NBATCH + bg0 + bb] = rs2; } \
    } \
  } else { \
    const int j2 = pairIdx - 32; \
    float* stg2 = (float*)(smem + STG2B) + (wnp >> 1) * 896; \
    const float db1v = db1[j2*16 + lo16]; \
    const float dw2v = dW2[j2*16 + lo16]; \
    _Pragma("unroll") \
    for (int mf = 0; mf < 11; ++mf) { \
      _Pragma("unroll") \
      for (int e = 0; e < 4; ++e) { \
        const int r = mf*16 + 4*hi4 + e; \
        stg[r*33 + lo16]      = accA[mf][e]; \
        stg[r*33 + 16 + lo16] = accB[mf][e]; \
      } } \
    asm volatile("s_waitcnt lgkmcnt(0)" ::: "memory"); \
    _Pragma("unroll 1") \
    for (int it = 0; it < 4; ++it) { \
      const int bb = hi4 + 4*it; \
      float pi[11], pj[11]; \
      _Pragma("unroll") \
      for (int t = 0; t < 11; ++t) { \
        pi[t] = stg[(bb*11 + t)*33 + lo16] + db1v; \
        pj[t] = stg[(bb*11 + t)*33 + 16 + lo16]; \
      } \
      { /* pass 0: p 0..27 */ \
        float aP[28]; \
        _Pragma("unroll") \
        for (int p = 0; p < 28; ++p) \
          aP[p] = fmaxf(pi[II_[p]] + pj[JJ_[p]], 0.f) * dw2v; \
        _Pragma("unroll") \
        for (int p = 0; p < 28; ++p) { \
          aP[p] += __shfl_xor(aP[p], 1); \
          aP[p] += __shfl_xor(aP[p], 2); \
          aP[p] += __shfl_xor(aP[p], 4); \
          aP[p] += __shfl_xor(aP[p], 8); \
        } \
        _Pragma("unroll") \
        for (int p = 0; p < 28; ++p) \
          if (lo16 == (p & 15)) stg2[bb*56 + p] = aP[p]; \
      } \
      { /* pass 1: p 28..54 */ \
        float aP[27]; \
        _Pragma("unroll") \
        for (int p = 0; p < 27; ++p) \
          aP[p] = fmaxf(pi[II_[p+28]] + pj[JJ_[p+28]], 0.f) * dw2v; \
        _Pragma("unroll") \
        for (int p = 0; p < 27; ++p) { \
          aP[p] += __shfl_xor(aP[p], 1); \
          aP[p] += __shfl_xor(aP[p], 2); \
          aP[p] += __shfl_xor(aP[p], 4); \
          aP[p] += __shfl_xor(aP[p], 8); \
        } \
        _Pragma("unroll") \
        for (int p = 0; p < 27; ++p) \
          if (lo16 == ((p+28) & 15)) stg2[bb*56 + (p+28)] = aP[p]; \
      } \
    } \
    asm volatile("s_waitcnt lgkmcnt(0)" ::: "memory"); \
    { /* coalesced copy stg2 -> g_partI[j2][bg0..bg0+15][56] */ \
      float* gdst = g_partI + ((size_t)j2*NBATCH + bg0) * 56; \
      _Pragma("unroll") \
      for (int i = 0; i < 14; ++i) gdst[ln + 64*i] = stg2[ln + 64*i]; \
    } \
  } \
} while(0)

__launch_bounds__(512, 4)
__global__ void energy_mfma(
    const float* __restrict__ kb1, const float* __restrict__ kW2,
    const float* __restrict__ lb1, const float* __restrict__ lW2,
    const float* __restrict__ db1, const float* __restrict__ dW2)
{
    extern __shared__ char smem[];
    const int tid  = threadIdx.x;
    const int wv   = tid >> 6, ln = tid & 63;
    const int lo16 = ln & 15, hi4 = ln >> 4;
    const int wm   = wv >> 2, wnp = wv & 3;        // 2M x 4PAIR waves
    const int bx   = blockIdx.x;
    const int n    = bx >> 6;                      // 0..23
    const int m    = bx & 63;                      // 0..63
    const int pairIdx = n*4 + wnp;
    const int bg0  = m*32 + wm*16;
    const int gi3  = (wv < 6) ? (wv + 24) : (wv + 22);

    f32x4 accA[11], accB[11];
    #pragma unroll
    for (int mf = 0; mf < 11; ++mf) {
        accA[mf] = (f32x4){0.f,0.f,0.f,0.f};
        accB[mf] = (f32x4){0.f,0.f,0.f,0.f};
    }

    // hoisted granule pointers (step-invariant base + constant stride)
    const char *s0, *s1, *s2, *s3;
    size_t st0, st1, st2, st3;
    int d0, d1, d2, d3;
    INITG(wv,      s0, st0, d0);
    INITG(wv + 8,  s1, st1, d1);
    INITG(wv + 16, s2, st2, d2);
    INITG(gi3,     s3, st3, d3);

    STAGE2(0);                                     // step 0 -> buf 0

    #pragma unroll 2
    for (int step = 0; step < 31; ++step) {
        STAGE2(((step + 1) & 1) * BUFSZ);          // next step -> other buf
        asm volatile("s_waitcnt vmcnt(4)" ::: "memory");   // this step's 4 done
        __builtin_amdgcn_s_barrier();
        MFMA_PHASE((step & 1) * BUFSZ);
        asm volatile("" ::: "memory");
        __builtin_amdgcn_s_barrier();              // all reads done before re-stage
    }
    asm volatile("s_waitcnt vmcnt(0)" ::: "memory");
    __builtin_amdgcn_s_barrier();
    MFMA_PHASE(BUFSZ);                             // step 31 (odd buf)
    asm volatile("" ::: "memory");
    __builtin_amdgcn_s_barrier();

    // epilogue: 4 rounds; 2 LDS regions (wnp>>1), aliasing dead staging buffers
    #pragma unroll 1
    for (int er = 0; er < 4; ++er) {
        if (wm == (er >> 1) && (wnp & 1) == (er & 1)) { EPILOGUE(); }
        __syncthreads();
    }
}

__global__ void finalize(
    const float* __restrict__ base_conf,
    const float* __restrict__ kb2, const float* __restrict__ lb2,
    const float* __restrict__ db2,
    const float* __restrict__ kwp, const float* __restrict__ lwp,
    const float* __restrict__ iwp, const float* __restrict__ tmpp,
    float* __restrict__ out)
{
    const int wv = threadIdx.x >> 6, ln = threadIdx.x & 63;
    const int b = blockIdx.x*4 + wv;               // 512 blocks x 4 waves x 1 batch
    const float kw = kwp[0], lw = lwp[0], iw = iwp[0], temp = tmpp[0];
    const float kb2v = kb2[0], lb2v = lb2[0], db2v = db2[0];

    // ---- interaction: lane = j2, 16B chunks, full-wave reduce ----
    float is = 0.f;
    const float* ibase = g_partI + ((size_t)ln*NBATCH + b)*56;
    #pragma unroll
    for (int c = 0; c < 14; ++c) {
        f32x4 v = *(const f32x4*)(ibase + c*4);
        #pragma unroll
        for (int msk = 1; msk <= 32; msk <<= 1) {
            v[0] += __shfl_xor(v[0], msk);
            v[1] += __shfl_xor(v[1], msk);
            v[2] += __shfl_xor(v[2], msk);
            v[3] += __shfl_xor(v[3], msk);
        }
        #pragma unroll
        for (int k = 0; k < 4; ++k) {
            const int p = c*4 + k;
            if (p < 55)
                is += fmaxf(v[k] + db2v, 0.f) *
                      (1.f / (float)(JJ_[p] - II_[p] + 1));
        }
    }

    // ---- kinetic: slots 0..15 ----
    float kv = (ln < 16) ? g_partKL[(size_t)ln*NBATCH + b] : 0.f;
    #pragma unroll
    for (int msk = 1; msk <= 32; msk <<= 1) kv += __shfl_xor(kv, msk);
    const float kinetic = -kw * (kv * (1.f/11.f) + kb2v);

    // ---- local: lane t<11 sums 16 j's, then gather ----
    float lv = 0.f;
    if (ln < 11) {
        #pragma unroll
        for (int j = 0; j < 16; ++j)
            lv += g_partKL[(size_t)(16 + j*11 + ln)*NBATCH + b];
    }
    float ls = 0.f;
    #pragma unroll
    for (int t = 0; t < 11; ++t)
        ls += fmaxf(__shfl(lv, t) + lb2v, 0.f);
    const float local_e = lw * (ls * (1.f/11.f));

    const float inter = iw * (is * (1.f/55.f));
    const float total = kinetic + local_e + inter;
    const float ec = 1.f / (1.f + expf(total / (fabsf(temp) + 0.1f)));
    if (ln == 0) {
        out[0*NBATCH + b] = total;
        out[1*NBATCH + b] = kinetic;
        out[2*NBATCH + b] = local_e;
        out[3*NBATCH + b] = inter;
        out[4*NBATCH + b] = ec;
        out[5*NBATCH + b] = base_conf[b] * ec;
    }
}

extern "C" void kernel_launch(void* const* d_in, const int* in_sizes, int n_in,
                              void* d_out, int out_size, void* d_ws, size_t ws_size,
                              hipStream_t stream) {
    const float* h_stack   = (const float*)d_in[0];
    const float* base_conf = (const float*)d_in[1];
    const float* kW1 = (const float*)d_in[2];
    const float* kb1 = (const float*)d_in[3];
    const float* kW2 = (const float*)d_in[4];
    const float* kb2 = (const float*)d_in[5];
    const float* lW1 = (const float*)d_in[6];
    const float* lb1 = (const float*)d_in[7];
    const float* lW2 = (const float*)d_in[8];
    const float* lb2 = (const float*)d_in[9];
    const float* dW1 = (const float*)d_in[10];
    const float* db1 = (const float*)d_in[11];
    const float* dW2 = (const float*)d_in[12];
    const float* db2 = (const float*)d_in[13];
    const float* kwp = (const float*)d_in[14];
    const float* lwp = (const float*)d_in[15];
    const float* iwp = (const float*)d_in[16];
    const float* tmpp= (const float*)d_in[17];
    float* out = (float*)d_out;

    hipLaunchKernelGGL(pack_A, dim3(11264), dim3(256), 0, stream, h_stack);
    hipLaunchKernelGGL(pack_weights, dim3(1536), dim3(256), 0, stream, kW1, lW1, dW1);

    hipFuncSetAttribute((const void*)energy_mfma,
                        hipFuncAttributeMaxDynamicSharedMemorySize, LDS_TOTAL);
    hipLaunchKernelGGL(energy_mfma, dim3(NBLOCKS), dim3(512), LDS_TOTAL, stream,
                       kb1, kW2, lb1, lW2, db1, dW2);

    hipLaunchKernelGGL(finalize, dim3(512), dim3(256), 0, stream,
                       base_conf, kb2, lb2, db2, kwp, lwp, iwp, tmpp, out);
}